// Round 4
// baseline (143.472 us; speedup 1.0000x reference)
//
#include <hip/hip_runtime.h>

// CritiGraph fused loss kernel, MI355X (gfx950). Round 4.
//
//  * voc_emb is DEAD in the reference (eu_val[:,64:] never used) -> never read.
//  * cos_similarity(c1,c2) = sgn * (clz(|c1|^|c2|+1)/16 - 1); pack (sign<<31)|abs so one
//    XOR yields the sign product (bit31) and abs-xor (low bits).
//  * |loc| < 2^16 -> abs-xor < 2^16 -> clz in [15,31]: only 34 (clz,sign) cases.
//    Round 4: LDS lookup tables (replicated x32 banks, lane -> bank tid&31, 2-way alias
//    free) give exp(cc) and cc directly -- no cvt/fma/sign/v_exp in the hot loop.
//  * Staged tables hold exp2(base) (product domain) + base (log domain, dyn .w only).
//  * loss_dyn_dyn = kl + lse_s(ct) - sum_s p_eu*ct ; loss_dyn_sta = lse_v(20ct) - 20ct[tar].
//  * 512-thread blocks (1 (c,p) pair per thread), grid=T: 4 waves/SIMD, staging once per t.

#define Tn   512
#define NC   65
#define TPd  8
#define NTn  64
#define KV   128
#define Sn   192
#define Dn   256
#define OUT1 (Tn * NC * TPd)
#define TABN 34          // (clz-15)*2 + signbit, clz in [15,31]
#define TABR (TABN * 32) // bank-replicated table stride (floats)

#define LOG2E 1.44269504088896340736f
#define LN2   0.69314718055994530942f
#define K1S (0.0625f * 2.5f * LOG2E)
#define K0S (-2.5f * LOG2E)

__device__ __forceinline__ float exp2_fast(float x) {
#if __has_builtin(__builtin_amdgcn_exp2f)
    return __builtin_amdgcn_exp2f(x);
#else
    return exp2f(x);
#endif
}
__device__ __forceinline__ int pack_loc(int v) {
    return (v < 0) ? (int)(0x80000000u | (unsigned)(-v)) : v;
}
__device__ __forceinline__ float asf(int v) { return __int_as_float(v); }

// raw cos (scale 1): sgn(y) * (clz(abs31(y)+1)/16 - 1)
__device__ __forceinline__ float cos_raw(int y) {
    int   x = (y & 0x7fffffff) + 1;
    float c = fmaf((float)__clz(x), 0.0625f, -1.0f);
    return __int_as_float(__float_as_int(c) ^ (y & 0x80000000));
}
// table index (0..33) from y
__device__ __forceinline__ int tab_idx(int y) {
    int x = (y & 0x7fffffff) + 1;
    int u = __clz(x) - 15;
    return u * 2 + (int)(((unsigned)y) >> 31);
}

__global__ __launch_bounds__(512, 4) void critigraph_kernel(
    const int*   __restrict__ cur_tar,
    const int*   __restrict__ cnc_loc,
    const int*   __restrict__ sta_loc,
    const int*   __restrict__ ttn_loc,
    const int*   __restrict__ voc_loc,
    const float* __restrict__ sta_emb,
    const float* __restrict__ ttn_emb,
    float*       __restrict__ out)
{
    __shared__ int4  s_dyn4[NTn * TPd];   // {apos, bits(exp2(b2d)), bits(peu), bits(b2d)} 8KB
    __shared__ int2  s_sta2[KV * TPd];    // {apos, bits(exp2(b2s))}                      8KB
    __shared__ float s_tab[3 * TABR];     // [eD | ccD | eS], each idx*32 + (tid&31)     12.75KB
    __shared__ int   s_cnc[NC * TPd];
    __shared__ int   s_staloc[TPd];
    __shared__ float s_csum[Sn];
    __shared__ float s_eu[NTn];
    __shared__ float s_peu[NTn];
    __shared__ float s_dotbase[TPd];
    __shared__ float s_kl;

    const int t   = blockIdx.x;
    const int tid = threadIdx.x;

    // ---- P0: pack sta/cnc; build replicated tables (no deps) ----
    if (tid < TPd) s_staloc[tid] = pack_loc(sta_loc[t * TPd + tid]);
    for (int i = tid; i < NC * TPd; i += 512)
        s_cnc[i] = pack_loc(cnc_loc[t * NC * TPd + i]);
    for (int i = tid; i < TABR; i += 512) {
        int   idx = i >> 5;
        int   clz = 15 + (idx >> 1);
        float mag = (float)clz * 0.0625f - 1.0f;            // cos magnitude
        float sgn = (idx & 1) ? -1.f : 1.f;
        float ccd = sgn * mag * (0.125f * LOG2E);
        float ccs = sgn * mag * (2.5f * LOG2E);
        s_tab[i]            = exp2_fast(ccd);
        s_tab[i + TABR]     = ccd;
        s_tab[i + 2 * TABR] = exp2_fast(ccs);
    }
    __syncthreads();

    // ---- P1: pos tables (packed + raw sp), csum via 8-lane shuffles; eu dot ----
    const int mysta = s_staloc[tid & 7];
    float mysp[3];
    #pragma unroll
    for (int k = 0; k < 3; ++k) {
        int i = tid + 512 * k;
        int s = i >> 3;
        int v = (s < NTn) ? ttn_loc[t * NTn * TPd + i]
                          : voc_loc[t * KV * TPd + (i - NTn * TPd)];
        int packed = pack_loc(v);
        float c = cos_raw(packed ^ mysta);
        mysp[k] = c;
        if (s < NTn) s_dyn4[i].x = packed;
        else         s_sta2[i - NTn * TPd].x = packed;
        float v8 = c;
        v8 += __shfl_xor(v8, 1);
        v8 += __shfl_xor(v8, 2);
        v8 += __shfl_xor(v8, 4);
        if ((tid & 7) == 0) s_csum[s] = v8;
    }
    {   // eu: 8 threads per row, 8 independent float4 loads each
        const int r = tid >> 3, q = tid & 7;
        const float4* A = (const float4*)(sta_emb + (size_t)t * Dn);
        const float4* B = (const float4*)(ttn_emb + ((size_t)t * NTn + r) * Dn);
        float acc = 0.f;
        #pragma unroll
        for (int k = 0; k < 8; ++k) {
            float4 a = A[k * 8 + q];
            float4 b = B[k * 8 + q];
            acc += a.x * b.x + a.y * b.y + a.z * b.z + a.w * b.w;
        }
        acc += __shfl_xor(acc, 1);
        acc += __shfl_xor(acc, 2);
        acc += __shfl_xor(acc, 4);
        if (q == 0) s_eu[r] = acc;                           // 20*TEMP = 1.0
    }
    __syncthreads();

    // ---- P2: finalize staged tables (exp2 of base); softmax over eu (wave 0) ----
    #pragma unroll
    for (int k = 0; k < 3; ++k) {
        int i = tid + 512 * k;
        int s = i >> 3;
        if (s < NTn) {
            float b2 = (s_csum[s] - mysp[k]) * (0.125f * LOG2E);
            s_dyn4[i].y = __float_as_int(exp2_fast(b2));
            s_dyn4[i].w = __float_as_int(b2);
        } else {
            float b2 = (s_csum[s] - mysp[k]) * (2.5f * LOG2E);
            s_sta2[i - NTn * TPd].y = __float_as_int(exp2_fast(b2));
        }
    }
    if (tid < 64) {
        float e  = s_eu[tid];
        float mx = e;
        #pragma unroll
        for (int m = 1; m < 64; m <<= 1) mx = fmaxf(mx, __shfl_xor(mx, m));
        float ex = __expf(e - mx);
        float z  = ex;
        #pragma unroll
        for (int m = 1; m < 64; m <<= 1) z += __shfl_xor(z, m);
        float pe = ex / z;
        s_peu[tid] = pe;
        float kls = pe * ((e - mx) - __logf(z));
        #pragma unroll
        for (int m = 1; m < 64; m <<= 1) kls += __shfl_xor(kls, m);
        if (tid == 0) s_kl = kls;
    }
    __syncthreads();

    // ---- P3: peu into dyn .z; dotbase[p] = sum_s peu[s]*b2d[s,p] (wave 0) ----
    s_dyn4[tid].z = __float_as_int(s_peu[tid >> 3]);
    if (tid < 64) {
        int g = tid & 7, j = tid >> 3;
        float a = 0.f;
        #pragma unroll
        for (int k = 0; k < 8; ++k) {
            int s = 8 * j + k;
            a = fmaf(s_peu[s], asf(s_dyn4[s * TPd + g].w), a);
        }
        #pragma unroll
        for (int m = 8; m < 64; m <<= 1) a += __shfl_xor(a, m);
        if (tid < TPd) s_dotbase[g] = a;
    }
    __syncthreads();

    // ---- P4: hot loop. One (c,p) pair per thread: c = tid>>3, p = tid&7 ----
    const int   p    = tid & 7;
    const int   acnc = s_cnc[tid];
    const int   tar  = cur_tar[t];
    const float kl   = s_kl;
    const float dtb  = s_dotbase[p];
    const float* tb  = s_tab + (tid & 31);    // per-lane bank, 2-way alias (free)

    float sum = 0.f, dot = 0.f;
    #pragma unroll 16
    for (int s = 0; s < NTn; ++s) {
        int4  ab  = s_dyn4[s * TPd + p];      // broadcast, conflict-free
        int   j   = tab_idx(ab.x ^ acnc) * 32;
        float eD  = tb[j];
        float ccD = tb[j + TABR];
        sum = fmaf(asf(ab.y), eD, sum);       // += exp2(b2d) * exp2(ccD)
        dot = fmaf(asf(ab.z), ccD, dot);      // += peu * ccD
    }
    float s2 = 0.f;
    #pragma unroll 16
    for (int v = 0; v < KV; ++v) {
        int2  ab = s_sta2[v * TPd + p];       // broadcast, conflict-free
        int   j  = tab_idx(ab.x ^ acnc) * 32;
        s2 = fmaf(asf(ab.y), tb[j + 2 * TABR], s2);
    }
    {   // target logit (log2-domain, recomputed once)
        int   ax  = s_sta2[tar * TPd + p].x;
        float sp  = cos_raw(ax ^ s_staloc[p]);
        float b2t = (s_csum[NTn + tar] - sp) * (2.5f * LOG2E);
        int   y   = ax ^ acnc;
        int   x   = (y & 0x7fffffff) + 1;
        float cct = fmaf((float)__clz(x), K1S, K0S);
        cct = __int_as_float(__float_as_int(cct) ^ (y & 0x80000000));
        float* od = out + (size_t)t * NC * TPd;
        float* os = out + OUT1 + (size_t)t * NC * TPd;
        od[tid] = kl + LN2 * (__log2f(sum) - (dtb + dot));
        os[tid] = LN2 * (__log2f(s2) - (b2t + cct));
    }

    // ---- P5: tail pair (c=64, p=w): one pair per wave, lane-split over s ----
    {
        const int w    = tid >> 6;
        const int lane = tid & 63;
        const int acw  = s_cnc[512 + w];
        float sumd, dotd, sums;
        {   // dyn: s = lane
            int4  ab = s_dyn4[lane * TPd + w];
            int   j  = tab_idx(ab.x ^ acw) * 32;
            sumd = asf(ab.y) * tb[j];
            dotd = asf(ab.z) * tb[j + TABR];
        }
        {   // sta: v = lane, lane+64
            int2 ab0 = s_sta2[lane * TPd + w];
            int2 ab1 = s_sta2[(lane + 64) * TPd + w];
            int  j0  = tab_idx(ab0.x ^ acw) * 32;
            int  j1  = tab_idx(ab1.x ^ acw) * 32;
            sums = asf(ab0.y) * tb[j0 + 2 * TABR] + asf(ab1.y) * tb[j1 + 2 * TABR];
        }
        #pragma unroll
        for (int m = 1; m < 64; m <<= 1) {
            sumd += __shfl_xor(sumd, m);
            dotd += __shfl_xor(dotd, m);
            sums += __shfl_xor(sums, m);
        }
        if (lane == 0) {
            int   ax  = s_sta2[tar * TPd + w].x;
            float sp  = cos_raw(ax ^ s_staloc[w]);
            float b2t = (s_csum[NTn + tar] - sp) * (2.5f * LOG2E);
            int   y   = ax ^ acw;
            int   x   = (y & 0x7fffffff) + 1;
            float cct = fmaf((float)__clz(x), K1S, K0S);
            cct = __int_as_float(__float_as_int(cct) ^ (y & 0x80000000));
            out[(size_t)t * NC * TPd + 512 + w] =
                kl + LN2 * (__log2f(sumd) - (s_dotbase[w] + dotd));
            out[OUT1 + (size_t)t * NC * TPd + 512 + w] =
                LN2 * (__log2f(sums) - (b2t + cct));
        }
    }
}

extern "C" void kernel_launch(void* const* d_in, const int* in_sizes, int n_in,
                              void* d_out, int out_size, void* d_ws, size_t ws_size,
                              hipStream_t stream) {
    (void)in_sizes; (void)n_in; (void)d_ws; (void)ws_size; (void)out_size;
    const int*   cur_tar = (const int*)  d_in[0];
    const int*   cnc_loc = (const int*)  d_in[1];
    const int*   sta_loc = (const int*)  d_in[2];
    const int*   ttn_loc = (const int*)  d_in[3];
    const int*   voc_loc = (const int*)  d_in[4];
    const float* sta_emb = (const float*)d_in[5];
    const float* ttn_emb = (const float*)d_in[6];
    // d_in[7] (voc_emb) intentionally unused: it only feeds eu_val[:,64:], discarded.
    critigraph_kernel<<<Tn, 512, 0, stream>>>(cur_tar, cnc_loc, sta_loc, ttn_loc,
                                              voc_loc, sta_emb, ttn_emb, (float*)d_out);
}

// Round 5
// 143.006 us; speedup vs baseline: 1.0033x; 1.0033x over previous
//
#include <hip/hip_runtime.h>

// CritiGraph fused loss kernel, MI355X (gfx950). Round 5.
//
//  * voc_emb is DEAD in the reference (eu_val[:,64:] never used) -> never read.
//  * cos_similarity(c1,c2) = sgn * (clz-form); locations are packed as
//    apos = (abs<<15) | (v<0): XOR of two packed values gives abs-xor in bits 15..30
//    and the sign product in bit 0. Then (y + 0x8000) = (absxor+1)<<15 | sgn exactly
//    (the <<15 headroom absorbs the +1 carry; max (65535+1)<<15 = 2^31 fits), so
//    e = 17 - clz(y+0x8000) and cos*scale = (clz-1) * (scale/16), sign via (y<<31)^bits.
//  * loss_dyn_dyn = kl + lse_s(ct) - sum_s p_eu*ct ; loss_dyn_sta = lse_v(20ct) - 20ct[tar].
//  * log2 domain throughout (LOG2E folded into staged tables & constants).
//  * Round-5 structure: VALU-centric hot loop (round 4's LDS tables were a wrong-way
//    trade: 1 shared DS pipe vs 4 SIMD VALU pipes). 8B/element, 2 elements per
//    ds_read_b128, layout [s/2][p][2] -> 96 DS instrs/wave. dyn element packs
//    {E=exp2(base) bf16, peu bf16} in one word (quantization error ~4e-3 << 0.15 budget).
//  * 512-thread blocks, 1 (c,p) pair/thread, __launch_bounds__(512,4) -> 4 waves/SIMD.

#define Tn   512
#define NC   65
#define TPd  8
#define NTn  64
#define KV   128
#define Sn   192
#define Dn   256
#define OUT1 (Tn * NC * TPd)

#define LOG2E 1.44269504088896340736f
#define LN2   0.69314718055994530942f
// cos*scale*LOG2E = (fclz - 1) * (scale * LOG2E / 16)
#define ADYN (0.125f * LOG2E * 0.0625f)
#define ASTA (2.5f  * LOG2E * 0.0625f)
#define ARAW 0.0625f

__device__ __forceinline__ float exp2_fast(float x) {
#if __has_builtin(__builtin_amdgcn_exp2f)
    return __builtin_amdgcn_exp2f(x);
#else
    return exp2f(x);
#endif
}
__device__ __forceinline__ float asf(int v) { return __int_as_float(v); }
__device__ __forceinline__ int   asi(float v) { return __float_as_int(v); }

// pack: (abs << 15) | (v < 0)
__device__ __forceinline__ int pack15(int v) {
    int a = (v < 0) ? -v : v;
    return (a << 15) | (int)(((unsigned)v) >> 31);
}
// signed scaled cos (log2 domain when A folded): (fclz-1)*A with sign from y bit0
__device__ __forceinline__ float cos15(int y, float A) {
    int   x = y + 0x8000;
    float c = fmaf((float)__clz(x), A, -A);
    return asf(asi(c) ^ (y << 31));
}

// remapped element index: 2 consecutive s for same p are contiguous (b128 = 2 elems)
__device__ __forceinline__ int eidx(int s, int p) {
    return ((s >> 1) * TPd + p) * 2 + (s & 1);
}

__global__ __launch_bounds__(512, 4) void critigraph_kernel(
    const int*   __restrict__ cur_tar,
    const int*   __restrict__ cnc_loc,
    const int*   __restrict__ sta_loc,
    const int*   __restrict__ ttn_loc,
    const int*   __restrict__ voc_loc,
    const float* __restrict__ sta_emb,
    const float* __restrict__ ttn_emb,
    float*       __restrict__ out)
{
    __shared__ int2  s_dyn2[NTn * TPd];   // {apos, E_bf16<<16 | peu_bf16}   4KB
    __shared__ int2  s_sta2[KV * TPd];    // {apos, bits(E f32)}             8KB
    __shared__ float s_b2d[NTn * TPd];    // log2-domain dyn base (for dotbase) 2KB
    __shared__ int   s_cnc[NC * TPd];     // pack15'd cnc_loc
    __shared__ int   s_staloc[TPd];
    __shared__ float s_csum[Sn];
    __shared__ float s_eu[NTn];
    __shared__ float s_peu[NTn];
    __shared__ float s_dotbase[TPd];
    __shared__ float s_kl;

    const int t   = blockIdx.x;
    const int tid = threadIdx.x;
    const int tar = cur_tar[t];           // uniform, early

    // ---- P0: pack sta/cnc locations ----
    if (tid < TPd) s_staloc[tid] = pack15(sta_loc[t * TPd + tid]);
    for (int i = tid; i < NC * TPd; i += 512)
        s_cnc[i] = pack15(cnc_loc[t * NC * TPd + i]);
    __syncthreads();

    // ---- P1: pos tables (packed apos + raw cos_sp), csum via 8-lane shuffles; eu dot ----
    const int mysta = s_staloc[tid & 7];
    float mysp[3];
    #pragma unroll
    for (int k = 0; k < 3; ++k) {
        int i = tid + 512 * k;
        int s = i >> 3;
        int p = i & 7;
        int v = (s < NTn) ? ttn_loc[t * NTn * TPd + i]
                          : voc_loc[t * KV * TPd + (i - NTn * TPd)];
        int packed = pack15(v);
        float c = cos15(packed ^ mysta, ARAW);             // raw cos_sp
        mysp[k] = c;
        if (s < NTn) s_dyn2[eidx(s, p)].x = packed;
        else         s_sta2[eidx(s - NTn, p)].x = packed;
        float v8 = c;
        v8 += __shfl_xor(v8, 1);
        v8 += __shfl_xor(v8, 2);
        v8 += __shfl_xor(v8, 4);
        if (p == 0) s_csum[s] = v8;
    }
    {   // eu: 8 threads per row, 8 independent float4 loads each
        const int r = tid >> 3, q = tid & 7;
        const float4* A = (const float4*)(sta_emb + (size_t)t * Dn);
        const float4* B = (const float4*)(ttn_emb + ((size_t)t * NTn + r) * Dn);
        float acc = 0.f;
        #pragma unroll
        for (int k = 0; k < 8; ++k) {
            float4 a = A[k * 8 + q];
            float4 b = B[k * 8 + q];
            acc += a.x * b.x + a.y * b.y + a.z * b.z + a.w * b.w;
        }
        acc += __shfl_xor(acc, 1);
        acc += __shfl_xor(acc, 2);
        acc += __shfl_xor(acc, 4);
        if (q == 0) s_eu[r] = acc;                          // 20*TEMP = 1.0
    }
    __syncthreads();

    // ---- P2: staged E tables (log2 domain, exp2'd); softmax over eu (wave 0) ----
    #pragma unroll
    for (int k = 0; k < 3; ++k) {
        int i = tid + 512 * k;
        int s = i >> 3;
        int p = i & 7;
        if (s < NTn) {
            float b2 = (s_csum[s] - mysp[k]) * (0.125f * LOG2E);
            int   e  = eidx(s, p);
            s_dyn2[e].y = asi(exp2_fast(b2));               // temp: E as f32
            s_b2d[e]    = b2;
        } else {
            float b2 = (s_csum[s] - mysp[k]) * (2.5f * LOG2E);
            s_sta2[eidx(s - NTn, p)].y = asi(exp2_fast(b2));
        }
    }
    if (tid < 64) {
        float e  = s_eu[tid];
        float mx = e;
        #pragma unroll
        for (int m = 1; m < 64; m <<= 1) mx = fmaxf(mx, __shfl_xor(mx, m));
        float ex = __expf(e - mx);
        float z  = ex;
        #pragma unroll
        for (int m = 1; m < 64; m <<= 1) z += __shfl_xor(z, m);
        float pe = ex / z;
        s_peu[tid] = pe;
        float kls = pe * ((e - mx) - __logf(z));
        #pragma unroll
        for (int m = 1; m < 64; m <<= 1) kls += __shfl_xor(kls, m);
        if (tid == 0) s_kl = kls;
    }
    __syncthreads();

    // ---- P3: pack {E bf16 | peu bf16} into dyn .y; dotbase[p] (wave 0) ----
    {
        int i = tid;                                        // remapped elem index
        int s = (((i >> 4) << 1) | (i & 1));
        int Eb = s_dyn2[i].y;
        int Pb = asi(s_peu[s]);
        s_dyn2[i].y = (int)((((unsigned)Eb + 0x8000u) & 0xFFFF0000u) |
                            (((unsigned)Pb + 0x8000u) >> 16));
    }
    if (tid < 64) {
        int g = tid & 7, j = tid >> 3;
        float a = 0.f;
        #pragma unroll
        for (int k = 0; k < 8; ++k) {
            int s = 8 * j + k;
            a = fmaf(s_peu[s], s_b2d[eidx(s, g)], a);
        }
        #pragma unroll
        for (int m = 8; m < 64; m <<= 1) a += __shfl_xor(a, m);
        if (tid < TPd) s_dotbase[g] = a;
    }
    __syncthreads();

    // ---- P4: hot loop. One (c,p) pair per thread: c = tid>>3, p = tid&7 ----
    const int   p    = tid & 7;
    const int   acnc = s_cnc[tid];
    const float kl   = s_kl;
    const float dtb  = s_dotbase[p];
    const int4* dyn4 = (const int4*)s_dyn2;   // [j*8+p] = elems s=2j, 2j+1
    const int4* sta4 = (const int4*)s_sta2;   // [j*8+p] = elems v=2j, 2j+1

    float sum = 0.f, dot = 0.f;
    #pragma unroll 8
    for (int j = 0; j < NTn / 2; ++j) {
        int4 q = dyn4[j * TPd + p];
        {   // elem s = 2j
            int   y  = q.x ^ acnc;
            float cc = cos15(y, ADYN);
            float E  = asf(q.y & (int)0xFFFF0000);
            float pe = asf(q.y << 16);
            sum = fmaf(E, exp2_fast(cc), sum);
            dot = fmaf(pe, cc, dot);
        }
        {   // elem s = 2j+1
            int   y  = q.z ^ acnc;
            float cc = cos15(y, ADYN);
            float E  = asf(q.w & (int)0xFFFF0000);
            float pe = asf(q.w << 16);
            sum = fmaf(E, exp2_fast(cc), sum);
            dot = fmaf(pe, cc, dot);
        }
    }
    float s2 = 0.f;
    #pragma unroll 8
    for (int j = 0; j < KV / 2; ++j) {
        int4 q = sta4[j * TPd + p];
        s2 = fmaf(asf(q.y), exp2_fast(cos15(q.x ^ acnc, ASTA)), s2);
        s2 = fmaf(asf(q.w), exp2_fast(cos15(q.z ^ acnc, ASTA)), s2);
    }
    {   // target logit + outputs
        int2  tq  = s_sta2[eidx(tar, p)];
        float b2t = __log2f(asf(tq.y));                    // = staged base (exact to 1e-6)
        float cct = cos15(tq.x ^ acnc, ASTA);
        float* od = out + (size_t)t * NC * TPd;
        float* os = out + OUT1 + (size_t)t * NC * TPd;
        od[tid] = kl + LN2 * (__log2f(sum) - (dtb + dot));
        os[tid] = LN2 * (__log2f(s2) - (b2t + cct));
    }

    // ---- P5: tail pair (c=64, p=w): one pair per wave, lane-split over s ----
    {
        const int w    = tid >> 6;
        const int lane = tid & 63;
        const int acw  = s_cnc[512 + w];
        float sumd, dotd, sums;
        {   // dyn: s = lane
            int2  q  = s_dyn2[eidx(lane, w)];
            int   y  = q.x ^ acw;
            float cc = cos15(y, ADYN);
            sumd = asf(q.y & (int)0xFFFF0000) * exp2_fast(cc);
            dotd = asf(q.y << 16) * cc;
        }
        {   // sta: v = lane, lane+64
            int2 q0 = s_sta2[eidx(lane, w)];
            int2 q1 = s_sta2[eidx(lane + 64, w)];
            sums = asf(q0.y) * exp2_fast(cos15(q0.x ^ acw, ASTA))
                 + asf(q1.y) * exp2_fast(cos15(q1.x ^ acw, ASTA));
        }
        #pragma unroll
        for (int m = 1; m < 64; m <<= 1) {
            sumd += __shfl_xor(sumd, m);
            dotd += __shfl_xor(dotd, m);
            sums += __shfl_xor(sums, m);
        }
        if (lane == 0) {
            int2  tq  = s_sta2[eidx(tar, w)];
            float b2t = __log2f(asf(tq.y));
            float cct = cos15(tq.x ^ acw, ASTA);
            out[(size_t)t * NC * TPd + 512 + w] =
                kl + LN2 * (__log2f(sumd) - (s_dotbase[w] + dotd));
            out[OUT1 + (size_t)t * NC * TPd + 512 + w] =
                LN2 * (__log2f(sums) - (b2t + cct));
        }
    }
}

extern "C" void kernel_launch(void* const* d_in, const int* in_sizes, int n_in,
                              void* d_out, int out_size, void* d_ws, size_t ws_size,
                              hipStream_t stream) {
    (void)in_sizes; (void)n_in; (void)d_ws; (void)ws_size; (void)out_size;
    const int*   cur_tar = (const int*)  d_in[0];
    const int*   cnc_loc = (const int*)  d_in[1];
    const int*   sta_loc = (const int*)  d_in[2];
    const int*   ttn_loc = (const int*)  d_in[3];
    const int*   voc_loc = (const int*)  d_in[4];
    const float* sta_emb = (const float*)d_in[5];
    const float* ttn_emb = (const float*)d_in[6];
    // d_in[7] (voc_emb) intentionally unused: it only feeds eu_val[:,64:], discarded.
    critigraph_kernel<<<Tn, 512, 0, stream>>>(cur_tar, cnc_loc, sta_loc, ttn_loc,
                                              voc_loc, sta_emb, ttn_emb, (float*)d_out);
}